// Round 1
// baseline (233.315 us; speedup 1.0000x reference)
//
#include <hip/hip_runtime.h>

#define TT 1000
#define CC 3
#define HH 64
#define WW 64
#define HW 4096
#define CHW 12288
#define CHW4 3072            // CHW / 4
#define NCHUNK 250
#define CLEN 4               // NCHUNK*CLEN == TT
#define WP 68                // padded LDS row length (elements)

// bf16 <-> f32 helpers (bf16 = top 16 bits of f32; RNE on encode)
__device__ __forceinline__ float bf2f(unsigned short u) {
    return __uint_as_float(((unsigned)u) << 16);
}
__device__ __forceinline__ unsigned short f2bf(float f) {
    unsigned u = __float_as_uint(f);
    return (unsigned short)((u + 0x7FFFu + ((u >> 16) & 1u)) >> 16);
}

// out[0:CHW] = x[0:CHW] (f32)
__global__ __launch_bounds__(256) void copy_out0_kernel(const float4* __restrict__ x,
                                                        float4* __restrict__ out) {
    int i = blockIdx.x * 256 + threadIdx.x;
    if (i < CHW4) out[i] = x[i];
}

// Iteration 1: conv(x[t]) for the block's chunk of CLEN t's, fused with chunk sums.
// Block = 1024 threads = full 64x64 image; thread owns 3ch x 1row x 4cols.
// f32 LDS staging (iter-1 conv must consume f32 x, matching the verified numerics).
__global__ __launch_bounds__(1024) void conv1_kernel(const float* __restrict__ x,
                                                     const float* __restrict__ cw,
                                                     const float* __restrict__ temb,
                                                     const int* __restrict__ tarr,
                                                     const float* __restrict__ ec,
                                                     unsigned short* __restrict__ Aout,
                                                     float* __restrict__ S) {
    __shared__ float st[CC][HH][WP];
    int tid = threadIdx.x;
    int w4 = tid & 15;
    int h  = tid >> 4;
    int w0 = w4 * 4;
    int c  = blockIdx.x;
    int t0 = c * CLEN;

    float sum[CC][4];
    #pragma unroll
    for (int co = 0; co < CC; ++co)
        #pragma unroll
        for (int k = 0; k < 4; ++k) sum[co][k] = 0.f;

    #pragma unroll
    for (int i = 0; i < CLEN; ++i) {
        int t = t0 + i;
        // stage own 12 elems of x[t]
        float4 m[CC];
        #pragma unroll
        for (int ch = 0; ch < CC; ++ch)
            m[ch] = *(const float4*)(x + (size_t)t * CHW + ch * HW + h * WW + w0);
        if (i > 0) __syncthreads();          // previous iteration's LDS reads done
        #pragma unroll
        for (int ch = 0; ch < CC; ++ch)
            *(float4*)&st[ch][h][w0] = m[ch];
        __syncthreads();

        float acc[CC][4];
        #pragma unroll
        for (int co = 0; co < CC; ++co)
            #pragma unroll
            for (int k = 0; k < 4; ++k) acc[co][k] = 0.f;

        #pragma unroll
        for (int ch = 0; ch < CC; ++ch) {
            #pragma unroll
            for (int dh = 0; dh < 3; ++dh) {
                int r = h - 1 + dh;
                float4 M = make_float4(0.f, 0.f, 0.f, 0.f);
                if ((unsigned)r < (unsigned)HH) M = *(const float4*)&st[ch][r][w0];
                float left  = __shfl_up(M.w, 1);   if (w4 == 0)  left  = 0.f;
                float right = __shfl_down(M.x, 1); if (w4 == 15) right = 0.f;
                float win[6] = {left, M.x, M.y, M.z, M.w, right};
                #pragma unroll
                for (int co = 0; co < CC; ++co) {
                    float wa = cw[((co * CC + ch) * 3 + dh) * 3 + 0];
                    float wb = cw[((co * CC + ch) * 3 + dh) * 3 + 1];
                    float wc = cw[((co * CC + ch) * 3 + dh) * 3 + 2];
                    #pragma unroll
                    for (int k = 0; k < 4; ++k)
                        acc[co][k] += win[k] * wa + win[k + 1] * wb + win[k + 2] * wc;
                }
            }
        }

        float e = ec[t];
        int tr = tarr[t];
        #pragma unroll
        for (int co = 0; co < CC; ++co) {
            float b = temb[tr * CC + co];
            ushort4 u;
            u.x = f2bf(e * (acc[co][0] + b));
            u.y = f2bf(e * (acc[co][1] + b));
            u.z = f2bf(e * (acc[co][2] + b));
            u.w = f2bf(e * (acc[co][3] + b));
            *(ushort4*)(Aout + (size_t)t * CHW + co * HW + h * WW + w0) = u;
            sum[co][0] += bf2f(u.x); sum[co][1] += bf2f(u.y);
            sum[co][2] += bf2f(u.z); sum[co][3] += bf2f(u.w);
        }
    }

    #pragma unroll
    for (int co = 0; co < CC; ++co)
        *(float4*)(S + (size_t)c * CHW + co * HW + h * WW + w0) =
            make_float4(sum[co][0], sum[co][1], sum[co][2], sum[co][3]);
}

// Fused final(iter k) + conv(iter k+1) + chunk-sum(iter k+1).
// Reads A_k (bf16 ets of iter k) + scanned offsets S; reconstructs the bf16 state
// in-register/LDS (never touching global); writes A_{k+1} and new sums into S (in place).
__global__ __launch_bounds__(1024) void fused_kernel(const unsigned short* __restrict__ Ain,
                                                     const float* __restrict__ x,   // x[0] = xT
                                                     float* __restrict__ S,
                                                     unsigned short* __restrict__ Aout,
                                                     const float* __restrict__ cw,
                                                     const float* __restrict__ temb,
                                                     const int* __restrict__ tarr,
                                                     const float* __restrict__ ec,
                                                     const float* __restrict__ ar,
                                                     const float* __restrict__ epc) {
    __shared__ unsigned short st[CC][HH][WP];
    int tid = threadIdx.x;
    int w4 = tid & 15;
    int h  = tid >> 4;
    int w0 = w4 * 4;
    int c  = blockIdx.x;
    int t0 = c * CLEN;

    float xT[CC][4], run[CC][4], state[CC][4], sum[CC][4];
    #pragma unroll
    for (int ch = 0; ch < CC; ++ch) {
        int off = ch * HW + h * WW + w0;
        float4 xv = *(const float4*)(x + off);                    // xT slice
        float4 rv = *(const float4*)(S + (size_t)c * CHW + off);  // exclusive chunk offset
        xT[ch][0] = xv.x; xT[ch][1] = xv.y; xT[ch][2] = xv.z; xT[ch][3] = xv.w;
        run[ch][0] = rv.x; run[ch][1] = rv.y; run[ch][2] = rv.z; run[ch][3] = rv.w;
        #pragma unroll
        for (int k = 0; k < 4; ++k) sum[ch][k] = 0.f;
    }

    // state entering this chunk: x^k[t0] = xT (c==0) or ar[t0-1]*xT + epc[t0-1]*off
    if (c == 0) {
        #pragma unroll
        for (int ch = 0; ch < CC; ++ch)
            #pragma unroll
            for (int k = 0; k < 4; ++k) state[ch][k] = xT[ch][k];
    } else {
        float a = ar[t0 - 1], p = epc[t0 - 1];
        #pragma unroll
        for (int ch = 0; ch < CC; ++ch)
            #pragma unroll
            for (int k = 0; k < 4; ++k)
                state[ch][k] = a * xT[ch][k] + p * run[ch][k];
    }
    // publish state (bf16 — same rounding the old X-array path had)
    #pragma unroll
    for (int ch = 0; ch < CC; ++ch) {
        ushort4 u;
        u.x = f2bf(state[ch][0]); u.y = f2bf(state[ch][1]);
        u.z = f2bf(state[ch][2]); u.w = f2bf(state[ch][3]);
        *(ushort4*)&st[ch][h][w0] = u;
    }
    __syncthreads();

    #pragma unroll
    for (int i = 0; i < CLEN; ++i) {
        int t = t0 + i;

        // prefetch A_k[t] (needed only for the state advance)
        ushort4 av[CC];
        if (i < CLEN - 1) {
            #pragma unroll
            for (int ch = 0; ch < CC; ++ch)
                av[ch] = *(const ushort4*)(Ain + (size_t)t * CHW + ch * HW + h * WW + w0);
        }

        // conv on bf16 state tile
        float acc[CC][4];
        #pragma unroll
        for (int co = 0; co < CC; ++co)
            #pragma unroll
            for (int k = 0; k < 4; ++k) acc[co][k] = 0.f;

        #pragma unroll
        for (int ch = 0; ch < CC; ++ch) {
            #pragma unroll
            for (int dh = 0; dh < 3; ++dh) {
                int r = h - 1 + dh;
                float4 M = make_float4(0.f, 0.f, 0.f, 0.f);
                if ((unsigned)r < (unsigned)HH) {
                    ushort4 u = *(const ushort4*)&st[ch][r][w0];
                    M = make_float4(bf2f(u.x), bf2f(u.y), bf2f(u.z), bf2f(u.w));
                }
                float left  = __shfl_up(M.w, 1);   if (w4 == 0)  left  = 0.f;
                float right = __shfl_down(M.x, 1); if (w4 == 15) right = 0.f;
                float win[6] = {left, M.x, M.y, M.z, M.w, right};
                #pragma unroll
                for (int co = 0; co < CC; ++co) {
                    float wa = cw[((co * CC + ch) * 3 + dh) * 3 + 0];
                    float wb = cw[((co * CC + ch) * 3 + dh) * 3 + 1];
                    float wc = cw[((co * CC + ch) * 3 + dh) * 3 + 2];
                    #pragma unroll
                    for (int k = 0; k < 4; ++k)
                        acc[co][k] += win[k] * wa + win[k + 1] * wb + win[k + 2] * wc;
                }
            }
        }

        float e = ec[t];
        int tr = tarr[t];
        #pragma unroll
        for (int co = 0; co < CC; ++co) {
            float b = temb[tr * CC + co];
            ushort4 u;
            u.x = f2bf(e * (acc[co][0] + b));
            u.y = f2bf(e * (acc[co][1] + b));
            u.z = f2bf(e * (acc[co][2] + b));
            u.w = f2bf(e * (acc[co][3] + b));
            *(ushort4*)(Aout + (size_t)t * CHW + co * HW + h * WW + w0) = u;
            sum[co][0] += bf2f(u.x); sum[co][1] += bf2f(u.y);
            sum[co][2] += bf2f(u.z); sum[co][3] += bf2f(u.w);
        }

        // advance state to x^k[t+1] = ar[t]*xT + epc[t]*(off + incl-sum A_k[..t])
        if (i < CLEN - 1) {
            float a = ar[t], p = epc[t];
            #pragma unroll
            for (int ch = 0; ch < CC; ++ch) {
                run[ch][0] += bf2f(av[ch].x); run[ch][1] += bf2f(av[ch].y);
                run[ch][2] += bf2f(av[ch].z); run[ch][3] += bf2f(av[ch].w);
                #pragma unroll
                for (int k = 0; k < 4; ++k)
                    state[ch][k] = a * xT[ch][k] + p * run[ch][k];
            }
            __syncthreads();                 // all conv reads of old tile done
            #pragma unroll
            for (int ch = 0; ch < CC; ++ch) {
                ushort4 u;
                u.x = f2bf(state[ch][0]); u.y = f2bf(state[ch][1]);
                u.z = f2bf(state[ch][2]); u.w = f2bf(state[ch][3]);
                *(ushort4*)&st[ch][h][w0] = u;
            }
            __syncthreads();                 // new tile visible
        }
    }

    // write new chunk sums (in place over the consumed offsets — block-private slot)
    #pragma unroll
    for (int co = 0; co < CC; ++co)
        *(float4*)(S + (size_t)c * CHW + co * HW + h * WW + w0) =
            make_float4(sum[co][0], sum[co][1], sum[co][2], sum[co][3]);
}

// Wave-parallel in-place exclusive scan over the chunk axis.
// One wave per float4 column (3072 columns); shfl-scan 64 chunks per segment.
__global__ __launch_bounds__(256) void scan_kernel(float4* __restrict__ S) {
    int gid  = blockIdx.x * 256 + threadIdx.x;
    int wid  = gid >> 6;                    // pos4 column, 0..3071
    int lane = threadIdx.x & 63;
    float4 carry = make_float4(0.f, 0.f, 0.f, 0.f);
    #pragma unroll
    for (int seg = 0; seg < (NCHUNK + 63) / 64; ++seg) {
        int cc = seg * 64 + lane;
        float4 v = make_float4(0.f, 0.f, 0.f, 0.f);
        if (cc < NCHUNK) v = S[(size_t)cc * CHW4 + wid];
        float4 incl = v;
        #pragma unroll
        for (int d = 1; d < 64; d <<= 1) {
            float tx = __shfl_up(incl.x, d), ty = __shfl_up(incl.y, d);
            float tz = __shfl_up(incl.z, d), tw = __shfl_up(incl.w, d);
            if (lane >= d) { incl.x += tx; incl.y += ty; incl.z += tz; incl.w += tw; }
        }
        float4 ex;
        ex.x = __shfl_up(incl.x, 1); ex.y = __shfl_up(incl.y, 1);
        ex.z = __shfl_up(incl.z, 1); ex.w = __shfl_up(incl.w, 1);
        if (lane == 0) ex = make_float4(0.f, 0.f, 0.f, 0.f);
        if (cc < NCHUNK)
            S[(size_t)cc * CHW4 + wid] = make_float4(carry.x + ex.x, carry.y + ex.y,
                                                     carry.z + ex.z, carry.w + ex.w);
        carry.x += __shfl(incl.x, 63); carry.y += __shfl(incl.y, 63);
        carry.z += __shfl(incl.z, 63); carry.w += __shfl(incl.w, 63);
    }
}

// Final iteration's state materialization: out[t+1] = ar[t]*xT + epc[t]*(off + running A_3)
__global__ __launch_bounds__(256) void final_kernel(const unsigned short* __restrict__ A,
                                                    const float4* __restrict__ S,
                                                    const float4* __restrict__ xT,
                                                    const float* __restrict__ ar,
                                                    const float* __restrict__ epc,
                                                    float4* __restrict__ out) {
    int ch = blockIdx.x / 12;               // chunk, block-uniform
    int pos4 = (blockIdx.x % 12) * 256 + threadIdx.x;
    float4 acc = S[(size_t)ch * CHW4 + pos4];
    float4 xv = xT[pos4];
    const unsigned short* p = A + (size_t)ch * CLEN * CHW + pos4 * 4;
    float4* qf = out + (size_t)(ch * CLEN + 1) * CHW4 + pos4;
    #pragma unroll
    for (int i = 0; i < CLEN; ++i) {
        int t = ch * CLEN + i;              // block-uniform -> s_load
        ushort4 u = *(const ushort4*)(p + (size_t)i * CHW);
        acc.x += bf2f(u.x); acc.y += bf2f(u.y); acc.z += bf2f(u.z); acc.w += bf2f(u.w);
        float a = ar[t], e = epc[t];
        qf[(size_t)i * CHW4] = make_float4(a * xv.x + e * acc.x, a * xv.y + e * acc.y,
                                           a * xv.z + e * acc.z, a * xv.w + e * acc.w);
    }
}

extern "C" void kernel_launch(void* const* d_in, const int* in_sizes, int n_in,
                              void* d_out, int out_size, void* d_ws, size_t ws_size,
                              hipStream_t stream) {
    const float* x    = (const float*)d_in[0];   // (T+1, C, H, W)
    const int*   tarr = (const int*)  d_in[1];   // (T,)
    const float* ar   = (const float*)d_in[2];   // (T,1,1,1)
    const float* ec   = (const float*)d_in[3];   // (T,1,1,1)
    const float* epc  = (const float*)d_in[4];   // (T,1,1,1)
    const float* cw   = (const float*)d_in[5];   // (C,C,3,3)
    const float* temb = (const float*)d_in[6];   // (T,C)
    float* out = (float*)d_out;                  // (T+1, C, H, W)

    unsigned short* A1 = (unsigned short*)d_ws;          // TT*CHW bf16 (24.6 MB)
    unsigned short* A2 = A1 + (size_t)TT * CHW;          // TT*CHW bf16 (24.6 MB)
    float* S = (float*)(A2 + (size_t)TT * CHW);          // NCHUNK*CHW f32 (12.3 MB)

    // out[0] = xT (f32)
    copy_out0_kernel<<<12, 256, 0, stream>>>((const float4*)x, (float4*)out);

    // iter 1: conv(x f32) + chunk sums
    conv1_kernel<<<NCHUNK, 1024, 0, stream>>>(x, cw, temb, tarr, ec, A1, S);
    scan_kernel<<<768, 256, 0, stream>>>((float4*)S);

    // iter-boundary fusions: final_k + conv_{k+1} + sums_{k+1}; state never hits global
    fused_kernel<<<NCHUNK, 1024, 0, stream>>>(A1, x, S, A2, cw, temb, tarr, ec, ar, epc);
    scan_kernel<<<768, 256, 0, stream>>>((float4*)S);
    fused_kernel<<<NCHUNK, 1024, 0, stream>>>(A2, x, S, A1, cw, temb, tarr, ec, ar, epc);
    scan_kernel<<<768, 256, 0, stream>>>((float4*)S);

    // iter 3 finalization: f32 output
    final_kernel<<<NCHUNK * 12, 256, 0, stream>>>(A1, (const float4*)S,
                                                  (const float4*)x, ar, epc, (float4*)out);
}